// Round 1
// 3002.528 us; speedup vs baseline: 2.2838x; 2.2838x over previous
//
#include <hip/hip_runtime.h>
#include <hip/hip_bf16.h>
#include <math.h>

typedef __hip_bfloat16 bf16;
typedef __bf16 bf16x8 __attribute__((ext_vector_type(8)));
typedef float f32x4 __attribute__((ext_vector_type(4)));

#define DIMC 1024
#define TLEN 2048
#define NBATCH 2
#define NHEADS 16
#define NE 8
#define NTOK 4096          // B*T
#define HIDN 4096          // 4*DIM
#define LNEPS 1e-5f

// flag-branched input load: f!=0 -> fp32, else bf16
__device__ __forceinline__ float ldf(const void* p, size_t i, int f) {
    return f ? ((const float*)p)[i] : __bfloat162float(((const bf16*)p)[i]);
}
__device__ __forceinline__ short f2b(float v) {
    bf16 h = __float2bfloat16(v);
    return *reinterpret_cast<short*>(&h);
}

// ---------------------------------------------------------------- dtype detect
__global__ void detect_kernel(const void* x, int* flag) {
    if (threadIdx.x == 0 && blockIdx.x == 0) {
        const bf16* xb = (const bf16*)x;
        float mx = 0.f;
        for (int i = 0; i < 256; i++) {
            float v = fabsf(__bfloat162float(xb[i]));
            if (isnan(v) || isinf(v)) v = 1e30f;
            mx = fmaxf(mx, v);
        }
        flag[0] = (mx < 1e3f) ? 0 : 1;   // 1 = inputs are fp32
    }
}

// ---------------------------------------------------------------- zero init
__global__ void zero_kernel(float* moe_out, unsigned* counts) {
    int i = blockIdx.x * 256 + threadIdx.x;
    if (i < NTOK * DIMC) moe_out[i] = 0.0f;
    if (i < NE) counts[i] = 0u;
}

// ---------------------------------------------------------------- layernorm
// one block per token; outputs fp32 (outf) and/or bf16 (outb)
__global__ __launch_bounds__(256) void ln_kernel(const void* xr, const float* xf,
                                                 const void* g, const void* b,
                                                 float* outf, short* outb,
                                                 const int* flag) {
    int f32 = *flag;
    int n = blockIdx.x;
    int tid = threadIdx.x;
    __shared__ float red[256];
    float v[4];
#pragma unroll
    for (int l = 0; l < 4; l++) {
        int c = l * 256 + tid;
        v[l] = xr ? ldf(xr, (size_t)n * DIMC + c, f32) : xf[(size_t)n * DIMC + c];
    }
    float s = v[0] + v[1] + v[2] + v[3];
    red[tid] = s; __syncthreads();
    for (int st = 128; st > 0; st >>= 1) { if (tid < st) red[tid] += red[tid + st]; __syncthreads(); }
    float mu = red[0] * (1.0f / DIMC);
    __syncthreads();
    float s2 = 0.f;
#pragma unroll
    for (int l = 0; l < 4; l++) { float d = v[l] - mu; s2 += d * d; }
    red[tid] = s2; __syncthreads();
    for (int st = 128; st > 0; st >>= 1) { if (tid < st) red[tid] += red[tid + st]; __syncthreads(); }
    float var = red[0] * (1.0f / DIMC);
    float rstd = rsqrtf(var + LNEPS);
#pragma unroll
    for (int l = 0; l < 4; l++) {
        int c = l * 256 + tid;
        float o = (v[l] - mu) * rstd * ldf(g, c, f32) + ldf(b, c, f32);
        if (outf) outf[(size_t)n * DIMC + c] = o;
        if (outb) outb[(size_t)n * DIMC + c] = f2b(o);
    }
}

// ---------------------------------------------------------------- fp32 GEMM (qkv / proj, unchanged)
__global__ __launch_bounds__(256) void gemm_f32(const float* __restrict__ A,
                                                const void* __restrict__ B,
                                                const void* __restrict__ resid,
                                                float* __restrict__ C,
                                                int M, int N, int K, const int* flag) {
    int f32 = *flag;
    __shared__ float As[64][17];
    __shared__ float Bs[16][64];
    int tid = threadIdx.x;
    int tx = tid & 15, ty = tid >> 4;
    int n0 = blockIdx.x * 64, m0 = blockIdx.y * 64;
    float acc[4][4] = {};
    for (int kk = 0; kk < K; kk += 16) {
#pragma unroll
        for (int l = 0; l < 4; l++) {
            int idx = tid + l * 256;
            int r = idx >> 4, c = idx & 15;
            As[r][c] = A[(size_t)(m0 + r) * K + kk + c];
        }
#pragma unroll
        for (int l = 0; l < 4; l++) {
            int idx = tid + l * 256;
            int kc = idx >> 6, nn = idx & 63;
            Bs[kc][nn] = ldf(B, (size_t)(kk + kc) * N + n0 + nn, f32);
        }
        __syncthreads();
#pragma unroll
        for (int kc = 0; kc < 16; kc++) {
            float a[4], bb[4];
#pragma unroll
            for (int i = 0; i < 4; i++) a[i] = As[ty * 4 + i][kc];
#pragma unroll
            for (int j = 0; j < 4; j++) bb[j] = Bs[kc][tx * 4 + j];
#pragma unroll
            for (int i = 0; i < 4; i++)
#pragma unroll
                for (int j = 0; j < 4; j++) acc[i][j] += a[i] * bb[j];
        }
        __syncthreads();
    }
#pragma unroll
    for (int i = 0; i < 4; i++) {
        int row = m0 + ty * 4 + i;
#pragma unroll
        for (int j = 0; j < 4; j++) {
            int col = n0 + tx * 4 + j;
            float r0 = resid ? ldf(resid, (size_t)row * N + col, f32) : 0.0f;
            C[(size_t)row * N + col] = acc[i][j] + r0;
        }
    }
}

// ---------------------------------------------------------------- attention: fp32 tiled flash
// grid: (TLEN/64, NBATCH*NHEADS), block 256 (4 waves).
// Each block: 64 queries of one (b,h). 4 threads cooperate per query
// (dpart = lane>>4 owns dims dpart*16..+15). K/V staged in LDS in 64-key
// tiles; online softmax in registers, mathematically identical to the
// previous serial kernel (fp32 throughout).
#define KB 64
#define KSTRIDE 72   // pad 64->72 floats: staging writes 2-way, reads conflict-free

__global__ __launch_bounds__(256) void attn_kernel(const float* __restrict__ qkv,
                                                   float* __restrict__ y) {
    int qblk = blockIdx.x;
    int bh = blockIdx.y; int b = bh >> 4, h = bh & 15;
    int tid = threadIdx.x;
    int lane = tid & 63;
    int wave = tid >> 6;
    int qid = lane & 15;       // query within wave
    int dpart = lane >> 4;     // 0..3: owns dims dpart*16..dpart*16+15
    int q = qblk * 64 + wave * 16 + qid;

    __shared__ float Ks[KB * KSTRIDE];
    __shared__ float Vs[KB * KSTRIDE];

    const float* base = qkv + (size_t)b * TLEN * 3 * DIMC;

    float qv[16];
    {
        const float* qrow = base + (size_t)q * 3 * DIMC + h * 64 + dpart * 16;
#pragma unroll
        for (int j = 0; j < 16; j++) qv[j] = qrow[j] * 0.125f;   // 1/sqrt(64)
    }
    float acc[16];
#pragma unroll
    for (int j = 0; j < 16; j++) acc[j] = 0.f;
    float m = -INFINITY, l = 0.f;

    int ntiles = qblk + 1;                 // causal: keys 0 .. qblk*64+63
    for (int t = 0; t < ntiles; t++) {
        int k0 = t * KB;
        __syncthreads();                   // protect previous tile's readers
        // cooperative stage: 64 rows x 64 cols, 256 threads x 4 float4 each
#pragma unroll
        for (int p4 = 0; p4 < 4; p4++) {
            int idx = tid + p4 * 256;
            int r = idx >> 4, c4 = idx & 15;
            const float* krow = base + (size_t)(k0 + r) * 3 * DIMC + DIMC + h * 64 + c4 * 4;
            *(f32x4*)&Ks[r * KSTRIDE + c4 * 4] = *(const f32x4*)krow;
            *(f32x4*)&Vs[r * KSTRIDE + c4 * 4] = *(const f32x4*)(krow + DIMC);
        }
        __syncthreads();
        bool diag = (t == ntiles - 1);
        for (int kk = 0; kk < KB; kk++) {
            const float* kr = &Ks[kk * KSTRIDE + dpart * 16];
            float s0 = 0.f, s1 = 0.f, s2 = 0.f, s3 = 0.f;
            {
                f32x4 c0 = *(const f32x4*)(kr);
                f32x4 c1 = *(const f32x4*)(kr + 4);
                f32x4 c2 = *(const f32x4*)(kr + 8);
                f32x4 c3 = *(const f32x4*)(kr + 12);
#pragma unroll
                for (int j = 0; j < 4; j++) {
                    s0 += qv[j]      * c0[j];
                    s1 += qv[4 + j]  * c1[j];
                    s2 += qv[8 + j]  * c2[j];
                    s3 += qv[12 + j] * c3[j];
                }
            }
            float p = (s0 + s1) + (s2 + s3);
            p += __shfl_xor(p, 16);        // reduce across the 4 dim-partitions
            p += __shfl_xor(p, 32);
            if (diag && (k0 + kk > q)) p = -INFINITY;
            if (p > m) {                   // rescale only on new max (exact)
                float alpha = __expf(m - p);   // m=-inf first time -> 0
                l *= alpha;
#pragma unroll
                for (int j = 0; j < 16; j++) acc[j] *= alpha;
                m = p;
            }
            float w = __expf(p - m);
            l += w;
            const float* vr = &Vs[kk * KSTRIDE + dpart * 16];
#pragma unroll
            for (int c = 0; c < 4; c++) {
                f32x4 vc = *(const f32x4*)(vr + c * 4);
#pragma unroll
                for (int j = 0; j < 4; j++) acc[c * 4 + j] += w * vc[j];
            }
        }
    }

    float invl = 1.0f / l;
    float* yrow = y + (size_t)(b * TLEN + q) * DIMC + h * 64 + dpart * 16;
#pragma unroll
    for (int c = 0; c < 4; c++) {
        f32x4 o;
#pragma unroll
        for (int j = 0; j < 4; j++) o[j] = acc[c * 4 + j] * invl;
        *(f32x4*)(yrow + c * 4) = o;
    }
}

// ---------------------------------------------------------------- router (unchanged, fp32-exact)
__global__ __launch_bounds__(256) void router_kernel(const float* __restrict__ h2,
                                                     const void* __restrict__ wr,
                                                     int* topi, float* topw,
                                                     unsigned* counts, const int* flag) {
    int f32 = *flag;
    int n = blockIdx.x, tid = threadIdx.x;
    __shared__ float sm[NE][256];
    float p[NE] = {};
#pragma unroll
    for (int l = 0; l < 4; l++) {
        int dd = l * 256 + tid;
        float hv = h2[(size_t)n * DIMC + dd];
#pragma unroll
        for (int e = 0; e < NE; e++) p[e] += hv * ldf(wr, (size_t)dd * NE + e, f32);
    }
#pragma unroll
    for (int e = 0; e < NE; e++) sm[e][tid] = p[e];
    __syncthreads();
    for (int st = 128; st > 0; st >>= 1) {
        if (tid < st)
#pragma unroll
            for (int e = 0; e < NE; e++) sm[e][tid] += sm[e][tid + st];
        __syncthreads();
    }
    if (tid == 0) {
        float lg[NE];
#pragma unroll
        for (int e = 0; e < NE; e++) lg[e] = sm[e][0];
        int i0 = 0;
        for (int e = 1; e < NE; e++) if (lg[e] > lg[i0]) i0 = e;
        int i1 = -1;
        for (int e = 0; e < NE; e++)
            if (e != i0 && (i1 < 0 || lg[e] > lg[i1])) i1 = e;
        float e1 = __expf(lg[i1] - lg[i0]);
        float inv = 1.0f / (1.0f + e1);
        topi[n * 2] = i0; topi[n * 2 + 1] = i1;
        topw[n * 2] = inv; topw[n * 2 + 1] = e1 * inv;
        atomicAdd(&counts[i0], 1u);
        atomicAdd(&counts[i1], 1u);
    }
}

__global__ void offsets_kernel(const unsigned* counts, unsigned* offsets, unsigned* cursor) {
    if (threadIdx.x == 0 && blockIdx.x == 0) {
        unsigned s = 0;
        for (int e = 0; e < NE; e++) { offsets[e] = s; s += counts[e]; cursor[e] = 0u; }
    }
}

__global__ void scatter_kernel(const int* topi, const unsigned* offsets,
                               unsigned* cursor, int* perm) {
    int n = blockIdx.x * 256 + threadIdx.x;
    if (n >= NTOK) return;
    for (int s = 0; s < 2; s++) {
        int e = topi[n * 2 + s];
        unsigned pos = atomicAdd(&cursor[e], 1u);
        perm[offsets[e] + pos] = n * 2 + s;
    }
}

// ---------------------------------------------------------------- transpose+cast to bf16
// in: raw (flag dtype) [z][R][C]  ->  out bf16 [z][C][R]
__global__ __launch_bounds__(256) void transpose_kernel(const void* __restrict__ in,
                                                        short* __restrict__ out,
                                                        int R, int C, const int* flag) {
    int f32 = *flag;
    __shared__ short t[32][33];
    int r0 = blockIdx.y * 32, c0 = blockIdx.x * 32;
    size_t base = (size_t)blockIdx.z * R * C;
    int tx = threadIdx.x & 31, ty = threadIdx.x >> 5;   // 32 x 8
#pragma unroll
    for (int i = ty; i < 32; i += 8)
        t[i][tx] = f2b(ldf(in, base + (size_t)(r0 + i) * C + c0 + tx, f32));
    __syncthreads();
#pragma unroll
    for (int i = ty; i < 32; i += 8)
        out[base + (size_t)(c0 + i) * R + r0 + tx] = t[tx][i];
}

// ---------------------------------------------------------------- MFMA GEMM for MoE
// MODE 2: he[slot] = gelu(h2b[tok(slot)] @ w1t[e]^T + b1[e])   (A gathered, out bf16)
// MODE 3: moe[tok] += topw[slot] * (he[slot] @ w2t[e]^T)       (atomic epilogue)
// Bt layout: [e][N][K] (pre-transposed, contiguous-in-k fragments).
// Layouts (verified m89): A-frag A[m=lane&15][k=quad*8+j]; B-frag B[k=quad*8+j][n=lane&15];
// C/D col=lane&15, row=quad*4+reg.
template<int MODE>
__global__ __launch_bounds__(256) void mfma_gemm(
    const short* __restrict__ A, const short* __restrict__ Bt,
    short* __restrict__ Cb, const void* __restrict__ bias,
    const int* __restrict__ perm, const unsigned* __restrict__ counts,
    const unsigned* __restrict__ offsets, const float* __restrict__ topw,
    float* __restrict__ moe_out,
    int N, int K, const int* flag)
{
    int e = blockIdx.z;
    int m0 = blockIdx.y * 64, n0 = blockIdx.x * 64;
    int cnt = (int)counts[e];
    if (m0 >= cnt) return;
    unsigned off = offsets[e];
    __shared__ int tokL[64];
    __shared__ float wL[64];
    int tid = threadIdx.x;
    if (tid < 64) {
        int rr = m0 + tid; if (rr >= cnt) rr = cnt - 1;
        int pair = perm[off + rr];
        tokL[tid] = pair >> 1;
        wL[tid] = topw[pair];
    }
    __syncthreads();

    int w = tid >> 6, lane = tid & 63, quad = lane >> 4, l15 = lane & 15;
    int wm = (w >> 1) * 32, wn = (w & 1) * 32;
    int ko = quad * 8;

    const short *a0p, *a1p;
    if (MODE == 2) {
        a0p = A + (size_t)tokL[wm + l15] * K;
        a1p = A + (size_t)tokL[wm + l15 + 16] * K;
    } else {
        int r0 = m0 + wm + l15;      if (r0 >= cnt) r0 = cnt - 1;
        int r1 = m0 + wm + l15 + 16; if (r1 >= cnt) r1 = cnt - 1;
        a0p = A + ((size_t)off + r0) * K;
        a1p = A + ((size_t)off + r1) * K;
    }
    const short* b0p = Bt + (size_t)e * N * K + (size_t)(n0 + wn + l15) * K;
    const short* b1p = b0p + (size_t)16 * K;

    f32x4 acc00 = {0.f,0.f,0.f,0.f}, acc01 = acc00, acc10 = acc00, acc11 = acc00;
#pragma unroll 4
    for (int kk = 0; kk < K; kk += 32) {
        bf16x8 a0 = *(const bf16x8*)(a0p + kk + ko);
        bf16x8 a1 = *(const bf16x8*)(a1p + kk + ko);
        bf16x8 b0 = *(const bf16x8*)(b0p + kk + ko);
        bf16x8 b1 = *(const bf16x8*)(b1p + kk + ko);
        acc00 = __builtin_amdgcn_mfma_f32_16x16x32_bf16(a0, b0, acc00, 0, 0, 0);
        acc01 = __builtin_amdgcn_mfma_f32_16x16x32_bf16(a0, b1, acc01, 0, 0, 0);
        acc10 = __builtin_amdgcn_mfma_f32_16x16x32_bf16(a1, b0, acc10, 0, 0, 0);
        acc11 = __builtin_amdgcn_mfma_f32_16x16x32_bf16(a1, b1, acc11, 0, 0, 0);
    }

    int f32 = (MODE == 2) ? *flag : 0;
#pragma unroll
    for (int mi = 0; mi < 2; mi++) {
#pragma unroll
        for (int ni = 0; ni < 2; ni++) {
            f32x4 acc = (mi == 0) ? (ni == 0 ? acc00 : acc01)
                                  : (ni == 0 ? acc10 : acc11);
            int col = n0 + wn + ni * 16 + l15;
#pragma unroll
            for (int reg = 0; reg < 4; reg++) {
                int row_local = wm + mi * 16 + quad * 4 + reg;
                if (m0 + row_local >= cnt) continue;
                float val = acc[reg];
                if (MODE == 2) {
                    val += ldf(bias, (size_t)e * N + col, f32);
                    val = 0.5f * val * (1.0f + erff(val * 0.70710678118f));
                    Cb[((size_t)off + m0 + row_local) * N + col] = f2b(val);
                } else {
                    int tok = tokL[row_local];
                    atomicAdd(&moe_out[(size_t)tok * N + col], val * wL[row_local]);
                }
            }
        }
    }
}

// ---------------------------------------------------------------- final: out = x2 + moe + sum_s w_s*b2[e_s]
__global__ void final_kernel(const float* x2, const float* moe,
                             const int* topi, const float* topw,
                             const void* b2, void* out, const int* flag) {
    int f32 = *flag;
    int i = blockIdx.x * 256 + threadIdx.x;
    int n = i >> 10, c = i & 1023;
    float v = x2[i] + moe[i];
#pragma unroll
    for (int s = 0; s < 2; s++)
        v += topw[n * 2 + s] * ldf(b2, (size_t)topi[n * 2 + s] * DIMC + c, f32);
    if (f32) ((float*)out)[i] = v;
    else     ((bf16*)out)[i] = __float2bfloat16(v);
}

// ================================================================ launch
extern "C" void kernel_launch(void* const* d_in, const int* in_sizes, int n_in,
                              void* d_out, int out_size, void* d_ws, size_t ws_size,
                              hipStream_t stream) {
    const void* x      = d_in[0];
    const void* ln1_g  = d_in[1];
    const void* ln1_b  = d_in[2];
    const void* w_attn = d_in[3];
    const void* w_proj = d_in[4];
    const void* ln2_g  = d_in[5];
    const void* ln2_b  = d_in[6];
    const void* w_rout = d_in[7];
    const void* w1     = d_in[8];
    const void* b1     = d_in[9];
    const void* w2     = d_in[10];
    const void* b2     = d_in[11];

    const size_t MT = (size_t)NTOK * DIMC;   // 4 M elements
    float* ws   = (float*)d_ws;
    float* h    = ws;                // MT
    float* qkv  = ws + MT;           // 3*MT   (dead after attn; he aliases here)
    float* y    = ws + 4 * MT;       // MT     (dead after proj)
    float* x2   = ws + 5 * MT;       // MT
    float* h2   = ws + 6 * MT;       // MT
    float* moe  = ws + 7 * MT;       // MT
    float* small = ws + 8 * MT;
    int*      topi    = (int*)small;                   // 8192
    float*    topw    = (float*)(topi + 2 * NTOK);     // 8192
    unsigned* counts  = (unsigned*)(topw + 2 * NTOK);  // 8
    unsigned* offsets = counts + NE;                   // 8
    unsigned* cursor  = offsets + NE;                  // 8
    int*      perm    = (int*)(cursor + NE);           // 8192
    int*      flag    = (int*)(perm + 2 * NTOK);       // 1
    // new bf16 buffers
    short* h2b  = (short*)(ws + 8 * MT + 32768);                 // MT bf16 = 8 MB
    short* w12t = (short*)(ws + 8 * MT + 32768 + MT / 2);        // 8*4096*1024 bf16 = 64 MB (w1t then w2t)
    short* he   = (short*)(ws + MT);                             // 8192*4096 bf16 = 64 MB (aliases qkv+y)

    // 0. detect input dtype
    detect_kernel<<<1, 64, 0, stream>>>(x, flag);
    // 1. zero moe accumulator + expert counts
    zero_kernel<<<dim3((MT + 255) / 256), 256, 0, stream>>>(moe, counts);
    // 2. LN1 -> h (fp32)
    ln_kernel<<<NTOK, 256, 0, stream>>>(x, nullptr, ln1_g, ln1_b, h, nullptr, flag);
    // 3. qkv = h @ w_attn
    gemm_f32<<<dim3(3 * DIMC / 64, NTOK / 64), 256, 0, stream>>>(h, w_attn, nullptr, qkv,
                                                                 NTOK, 3 * DIMC, DIMC, flag);
    // 4. attention (fp32 tiled flash: 64 queries/block, K/V tiles in LDS)
    attn_kernel<<<dim3(TLEN / 64, NBATCH * NHEADS), 256, 0, stream>>>(qkv, y);
    // 5. x2 = x + y @ w_proj
    gemm_f32<<<dim3(DIMC / 64, NTOK / 64), 256, 0, stream>>>(y, w_proj, x, x2,
                                                             NTOK, DIMC, DIMC, flag);
    // 6. LN2 -> h2 (fp32, router) + h2b (bf16, experts)
    ln_kernel<<<NTOK, 256, 0, stream>>>(nullptr, x2, ln2_g, ln2_b, h2, h2b, flag);
    // 7. router + top-2 (fp32-exact, unchanged)
    router_kernel<<<NTOK, 256, 0, stream>>>(h2, w_rout, topi, topw, counts, flag);
    // 8. prefix offsets
    offsets_kernel<<<1, 64, 0, stream>>>(counts, offsets, cursor);
    // 9. scatter token-slot ids by expert
    scatter_kernel<<<NTOK / 256, 256, 0, stream>>>(topi, offsets, cursor, perm);
    // 10. w1t[e][HIDN][DIMC] = w1[e][DIMC][HIDN]^T  (bf16)
    transpose_kernel<<<dim3(HIDN / 32, DIMC / 32, NE), 256, 0, stream>>>(w1, w12t, DIMC, HIDN, flag);
    // 11. GEMM1: he = gelu(gather(h2b) @ w1t^T + b1)
    mfma_gemm<2><<<dim3(HIDN / 64, NTOK / 64, NE), 256, 0, stream>>>(
        h2b, w12t, he, b1, perm, counts, offsets, topw, nullptr, HIDN, DIMC, flag);
    // 12. w2t[e][DIMC][HIDN] = w2[e][HIDN][DIMC]^T  (bf16, reuses w1t buffer)
    transpose_kernel<<<dim3(DIMC / 32, HIDN / 32, NE), 256, 0, stream>>>(w2, w12t, HIDN, DIMC, flag);
    // 13. GEMM2: moe[tok] += topw * (he @ w2t^T)
    mfma_gemm<3><<<dim3(DIMC / 64, NTOK / 64, NE), 256, 0, stream>>>(
        he, w12t, nullptr, nullptr, perm, counts, offsets, topw, moe, DIMC, HIDN, flag);
    // 14. out = x2 + moe + sum_s w_s * b2[e_s]
    final_kernel<<<dim3((MT + 255) / 256), 256, 0, stream>>>(x2, moe, topi, topw, b2,
                                                             (void*)d_out, flag);
}

// Round 3
// 2972.946 us; speedup vs baseline: 2.3065x; 1.0100x over previous
//
#include <hip/hip_runtime.h>
#include <hip/hip_bf16.h>
#include <math.h>

typedef __hip_bfloat16 bf16;
typedef __bf16 bf16x8 __attribute__((ext_vector_type(8)));
typedef float f32x4 __attribute__((ext_vector_type(4)));
typedef short s16x8 __attribute__((ext_vector_type(8)));

#define DIMC 1024
#define TLEN 2048
#define NBATCH 2
#define NHEADS 16
#define NE 8
#define NTOK 4096          // B*T
#define HIDN 4096          // 4*DIM
#define LNEPS 1e-5f

// flag-branched input load: f!=0 -> fp32, else bf16
__device__ __forceinline__ float ldf(const void* p, size_t i, int f) {
    return f ? ((const float*)p)[i] : __bfloat162float(((const bf16*)p)[i]);
}
__device__ __forceinline__ short f2b(float v) {
    bf16 h = __float2bfloat16(v);
    return *reinterpret_cast<short*>(&h);
}
__device__ __forceinline__ float b2f(short s) {
    bf16 h = *reinterpret_cast<bf16*>(&s);
    return __bfloat162float(h);
}

// ---------------------------------------------------------------- dtype detect
__global__ void detect_kernel(const void* x, int* flag) {
    if (threadIdx.x == 0 && blockIdx.x == 0) {
        const bf16* xb = (const bf16*)x;
        float mx = 0.f;
        for (int i = 0; i < 256; i++) {
            float v = fabsf(__bfloat162float(xb[i]));
            if (isnan(v) || isinf(v)) v = 1e30f;
            mx = fmaxf(mx, v);
        }
        flag[0] = (mx < 1e3f) ? 0 : 1;   // 1 = inputs are fp32
    }
}

// ---------------------------------------------------------------- zero init
__global__ void zero_kernel(float* moe_out, unsigned* counts) {
    int i = blockIdx.x * 256 + threadIdx.x;
    if (i < NTOK * DIMC) moe_out[i] = 0.0f;
    if (i < NE) counts[i] = 0u;
}

// ---------------------------------------------------------------- layernorm
// one block per token. Outputs: fp32 (outf) and/or bf16 split:
// o_hi always when non-null; o_mid/o_lo give 3-way split (fp32-exact repr).
__global__ __launch_bounds__(256) void ln_kernel(const void* xr, const float* xf,
                                                 const void* g, const void* b,
                                                 float* outf, short* o_hi,
                                                 short* o_mid, short* o_lo,
                                                 const int* flag) {
    int f32 = *flag;
    int n = blockIdx.x;
    int tid = threadIdx.x;
    __shared__ float red[256];
    float v[4];
#pragma unroll
    for (int l = 0; l < 4; l++) {
        int c = l * 256 + tid;
        v[l] = xr ? ldf(xr, (size_t)n * DIMC + c, f32) : xf[(size_t)n * DIMC + c];
    }
    float s = v[0] + v[1] + v[2] + v[3];
    red[tid] = s; __syncthreads();
    for (int st = 128; st > 0; st >>= 1) { if (tid < st) red[tid] += red[tid + st]; __syncthreads(); }
    float mu = red[0] * (1.0f / DIMC);
    __syncthreads();
    float s2 = 0.f;
#pragma unroll
    for (int l = 0; l < 4; l++) { float d = v[l] - mu; s2 += d * d; }
    red[tid] = s2; __syncthreads();
    for (int st = 128; st > 0; st >>= 1) { if (tid < st) red[tid] += red[tid + st]; __syncthreads(); }
    float var = red[0] * (1.0f / DIMC);
    float rstd = rsqrtf(var + LNEPS);
#pragma unroll
    for (int l = 0; l < 4; l++) {
        int c = l * 256 + tid;
        size_t idx = (size_t)n * DIMC + c;
        float o = (v[l] - mu) * rstd * ldf(g, c, f32) + ldf(b, c, f32);
        if (outf) outf[idx] = o;
        if (o_hi) {
            short h0 = f2b(o);
            o_hi[idx] = h0;
            if (o_mid) {
                float r = o - b2f(h0);
                short h1 = f2b(r);
                o_mid[idx] = h1;
                o_lo[idx] = f2b(r - b2f(h1));
            }
        }
    }
}

// ---------------------------------------------------------------- split-bf16 MFMA GEMM (qkv / proj)
// C[m][n] = sum_k A[m][k]*B[k][n] (+resid), fp32-exact-grade:
// A given as 3-way bf16 split (hi+mid+lo, repr error <= 2^-27).
// Bt given as [N][K] bf16 hi (+lo used only when flag=1 i.e. fp32 weights).
// Fragment layout identical to harness-verified mfma_gemm (m89).
__global__ __launch_bounds__(256) void gemm_split(
    const short* __restrict__ Ahi, const short* __restrict__ Amid,
    const short* __restrict__ Alo,
    const short* __restrict__ Bhi, const short* __restrict__ Blo,
    const void* __restrict__ resid, float* __restrict__ C,
    int N, int K, const int* flag)
{
    int f32 = *flag;
    int m0 = blockIdx.y * 64, n0 = blockIdx.x * 64;
    int tid = threadIdx.x;
    int w = tid >> 6, lane = tid & 63, quad = lane >> 4, l15 = lane & 15;
    int wm = (w >> 1) * 32, wn = (w & 1) * 32;
    int ko = quad * 8;

    size_t ra0 = (size_t)(m0 + wm + l15) * K + ko;
    size_t ra1 = ra0 + (size_t)16 * K;
    size_t rb0 = (size_t)(n0 + wn + l15) * K + ko;
    size_t rb1 = rb0 + (size_t)16 * K;

    f32x4 acc00 = {0.f,0.f,0.f,0.f}, acc01 = acc00, acc10 = acc00, acc11 = acc00;
    if (!f32) {
        // bf16 weights: B hi is exact, lo == 0 -> 12 MFMA / k-step
#pragma unroll 2
        for (int kk = 0; kk < K; kk += 32) {
            bf16x8 ah0 = *(const bf16x8*)(Ahi  + ra0 + kk);
            bf16x8 ah1 = *(const bf16x8*)(Ahi  + ra1 + kk);
            bf16x8 am0 = *(const bf16x8*)(Amid + ra0 + kk);
            bf16x8 am1 = *(const bf16x8*)(Amid + ra1 + kk);
            bf16x8 al0 = *(const bf16x8*)(Alo  + ra0 + kk);
            bf16x8 al1 = *(const bf16x8*)(Alo  + ra1 + kk);
            bf16x8 bh0 = *(const bf16x8*)(Bhi  + rb0 + kk);
            bf16x8 bh1 = *(const bf16x8*)(Bhi  + rb1 + kk);
            acc00 = __builtin_amdgcn_mfma_f32_16x16x32_bf16(ah0, bh0, acc00, 0, 0, 0);
            acc00 = __builtin_amdgcn_mfma_f32_16x16x32_bf16(am0, bh0, acc00, 0, 0, 0);
            acc00 = __builtin_amdgcn_mfma_f32_16x16x32_bf16(al0, bh0, acc00, 0, 0, 0);
            acc01 = __builtin_amdgcn_mfma_f32_16x16x32_bf16(ah0, bh1, acc01, 0, 0, 0);
            acc01 = __builtin_amdgcn_mfma_f32_16x16x32_bf16(am0, bh1, acc01, 0, 0, 0);
            acc01 = __builtin_amdgcn_mfma_f32_16x16x32_bf16(al0, bh1, acc01, 0, 0, 0);
            acc10 = __builtin_amdgcn_mfma_f32_16x16x32_bf16(ah1, bh0, acc10, 0, 0, 0);
            acc10 = __builtin_amdgcn_mfma_f32_16x16x32_bf16(am1, bh0, acc10, 0, 0, 0);
            acc10 = __builtin_amdgcn_mfma_f32_16x16x32_bf16(al1, bh0, acc10, 0, 0, 0);
            acc11 = __builtin_amdgcn_mfma_f32_16x16x32_bf16(ah1, bh1, acc11, 0, 0, 0);
            acc11 = __builtin_amdgcn_mfma_f32_16x16x32_bf16(am1, bh1, acc11, 0, 0, 0);
            acc11 = __builtin_amdgcn_mfma_f32_16x16x32_bf16(al1, bh1, acc11, 0, 0, 0);
        }
    } else {
        // fp32 weights: B 2-way split; terms ah*bh, ah*bl, am*bh, am*bl, al*bh
#pragma unroll 2
        for (int kk = 0; kk < K; kk += 32) {
            bf16x8 ah0 = *(const bf16x8*)(Ahi  + ra0 + kk);
            bf16x8 ah1 = *(const bf16x8*)(Ahi  + ra1 + kk);
            bf16x8 am0 = *(const bf16x8*)(Amid + ra0 + kk);
            bf16x8 am1 = *(const bf16x8*)(Amid + ra1 + kk);
            bf16x8 al0 = *(const bf16x8*)(Alo  + ra0 + kk);
            bf16x8 al1 = *(const bf16x8*)(Alo  + ra1 + kk);
            bf16x8 bh0 = *(const bf16x8*)(Bhi  + rb0 + kk);
            bf16x8 bh1 = *(const bf16x8*)(Bhi  + rb1 + kk);
            bf16x8 bl0 = *(const bf16x8*)(Blo  + rb0 + kk);
            bf16x8 bl1 = *(const bf16x8*)(Blo  + rb1 + kk);
            acc00 = __builtin_amdgcn_mfma_f32_16x16x32_bf16(ah0, bh0, acc00, 0, 0, 0);
            acc00 = __builtin_amdgcn_mfma_f32_16x16x32_bf16(ah0, bl0, acc00, 0, 0, 0);
            acc00 = __builtin_amdgcn_mfma_f32_16x16x32_bf16(am0, bh0, acc00, 0, 0, 0);
            acc00 = __builtin_amdgcn_mfma_f32_16x16x32_bf16(am0, bl0, acc00, 0, 0, 0);
            acc00 = __builtin_amdgcn_mfma_f32_16x16x32_bf16(al0, bh0, acc00, 0, 0, 0);
            acc01 = __builtin_amdgcn_mfma_f32_16x16x32_bf16(ah0, bh1, acc01, 0, 0, 0);
            acc01 = __builtin_amdgcn_mfma_f32_16x16x32_bf16(ah0, bl1, acc01, 0, 0, 0);
            acc01 = __builtin_amdgcn_mfma_f32_16x16x32_bf16(am0, bh1, acc01, 0, 0, 0);
            acc01 = __builtin_amdgcn_mfma_f32_16x16x32_bf16(am0, bl1, acc01, 0, 0, 0);
            acc01 = __builtin_amdgcn_mfma_f32_16x16x32_bf16(al0, bh1, acc01, 0, 0, 0);
            acc10 = __builtin_amdgcn_mfma_f32_16x16x32_bf16(ah1, bh0, acc10, 0, 0, 0);
            acc10 = __builtin_amdgcn_mfma_f32_16x16x32_bf16(ah1, bl0, acc10, 0, 0, 0);
            acc10 = __builtin_amdgcn_mfma_f32_16x16x32_bf16(am1, bh0, acc10, 0, 0, 0);
            acc10 = __builtin_amdgcn_mfma_f32_16x16x32_bf16(am1, bl0, acc10, 0, 0, 0);
            acc10 = __builtin_amdgcn_mfma_f32_16x16x32_bf16(al1, bh0, acc10, 0, 0, 0);
            acc11 = __builtin_amdgcn_mfma_f32_16x16x32_bf16(ah1, bh1, acc11, 0, 0, 0);
            acc11 = __builtin_amdgcn_mfma_f32_16x16x32_bf16(ah1, bl1, acc11, 0, 0, 0);
            acc11 = __builtin_amdgcn_mfma_f32_16x16x32_bf16(am1, bh1, acc11, 0, 0, 0);
            acc11 = __builtin_amdgcn_mfma_f32_16x16x32_bf16(am1, bl1, acc11, 0, 0, 0);
            acc11 = __builtin_amdgcn_mfma_f32_16x16x32_bf16(al1, bh1, acc11, 0, 0, 0);
        }
    }

#pragma unroll
    for (int mi = 0; mi < 2; mi++) {
#pragma unroll
        for (int ni = 0; ni < 2; ni++) {
            f32x4 acc = (mi == 0) ? (ni == 0 ? acc00 : acc01)
                                  : (ni == 0 ? acc10 : acc11);
            int col = n0 + wn + ni * 16 + l15;
#pragma unroll
            for (int reg = 0; reg < 4; reg++) {
                int row = m0 + wm + mi * 16 + quad * 4 + reg;
                float r0 = resid ? ldf(resid, (size_t)row * N + col, f32) : 0.0f;
                C[(size_t)row * N + col] = acc[reg] + r0;
            }
        }
    }
}

// ---------------------------------------------------------------- attention: fp32 tiled flash
// grid: (TLEN/64, NBATCH*NHEADS), block 256 (4 waves).
// Each block: 64 queries of one (b,h); 4 threads/query (dpart owns 16 dims).
// K/V staged in LDS, 64-key tiles; online softmax in fp32 registers.
// Output y emitted as 3-way bf16 split (fp32-exact) for the split proj GEMM.
#define KB 64
#define KSTRIDE 72   // pad 64->72 floats: staging writes 2-way, reads conflict-free

__global__ __launch_bounds__(256) void attn_kernel(const float* __restrict__ qkv,
                                                   short* __restrict__ yhi,
                                                   short* __restrict__ ymid,
                                                   short* __restrict__ ylo) {
    int qblk = gridDim.x - 1 - blockIdx.x;   // longest causal blocks first
    int bh = blockIdx.y; int b = bh >> 4, h = bh & 15;
    int tid = threadIdx.x;
    int lane = tid & 63;
    int wave = tid >> 6;
    int qid = lane & 15;       // query within wave
    int dpart = lane >> 4;     // 0..3: owns dims dpart*16..dpart*16+15
    int q = qblk * 64 + wave * 16 + qid;

    __shared__ float Ks[KB * KSTRIDE];
    __shared__ float Vs[KB * KSTRIDE];

    const float* base = qkv + (size_t)b * TLEN * 3 * DIMC;

    float qv[16];
    {
        const float* qrow = base + (size_t)q * 3 * DIMC + h * 64 + dpart * 16;
#pragma unroll
        for (int j = 0; j < 16; j++) qv[j] = qrow[j] * 0.125f;   // 1/sqrt(64)
    }
    float acc[16];
#pragma unroll
    for (int j = 0; j < 16; j++) acc[j] = 0.f;
    float m = -INFINITY, l = 0.f;

    int ntiles = qblk + 1;                 // causal: keys 0 .. qblk*64+63
    for (int t = 0; t < ntiles; t++) {
        int k0 = t * KB;
        __syncthreads();                   // protect previous tile's readers
#pragma unroll
        for (int p4 = 0; p4 < 4; p4++) {
            int idx = tid + p4 * 256;
            int r = idx >> 4, c4 = idx & 15;
            const float* krow = base + (size_t)(k0 + r) * 3 * DIMC + DIMC + h * 64 + c4 * 4;
            *(f32x4*)&Ks[r * KSTRIDE + c4 * 4] = *(const f32x4*)krow;
            *(f32x4*)&Vs[r * KSTRIDE + c4 * 4] = *(const f32x4*)(krow + DIMC);
        }
        __syncthreads();
        bool diag = (t == ntiles - 1);
        for (int kk = 0; kk < KB; kk++) {
            const float* kr = &Ks[kk * KSTRIDE + dpart * 16];
            float s0 = 0.f, s1 = 0.f, s2 = 0.f, s3 = 0.f;
            {
                f32x4 c0 = *(const f32x4*)(kr);
                f32x4 c1 = *(const f32x4*)(kr + 4);
                f32x4 c2 = *(const f32x4*)(kr + 8);
                f32x4 c3 = *(const f32x4*)(kr + 12);
#pragma unroll
                for (int j = 0; j < 4; j++) {
                    s0 += qv[j]      * c0[j];
                    s1 += qv[4 + j]  * c1[j];
                    s2 += qv[8 + j]  * c2[j];
                    s3 += qv[12 + j] * c3[j];
                }
            }
            float p = (s0 + s1) + (s2 + s3);
            p += __shfl_xor(p, 16);        // reduce across the 4 dim-partitions
            p += __shfl_xor(p, 32);
            if (diag && (k0 + kk > q)) p = -INFINITY;
            if (p > m) {                   // rescale only on new max (exact)
                float alpha = __expf(m - p);   // m=-inf first time -> 0
                l *= alpha;
#pragma unroll
                for (int j = 0; j < 16; j++) acc[j] *= alpha;
                m = p;
            }
            float w = __expf(p - m);
            l += w;
            const float* vr = &Vs[kk * KSTRIDE + dpart * 16];
#pragma unroll
            for (int c = 0; c < 4; c++) {
                f32x4 vc = *(const f32x4*)(vr + c * 4);
#pragma unroll
                for (int j = 0; j < 4; j++) acc[c * 4 + j] += w * vc[j];
            }
        }
    }

    float invl = 1.0f / l;
    size_t rowbase = (size_t)(b * TLEN + q) * DIMC + h * 64 + dpart * 16;
#pragma unroll
    for (int half = 0; half < 2; half++) {
        s16x8 oh, om, ol;
#pragma unroll
        for (int j = 0; j < 8; j++) {
            float v = acc[half * 8 + j] * invl;
            short h0 = f2b(v);
            float r = v - b2f(h0);
            short h1 = f2b(r);
            oh[j] = h0; om[j] = h1; ol[j] = f2b(r - b2f(h1));
        }
        *(s16x8*)(yhi  + rowbase + half * 8) = oh;
        *(s16x8*)(ymid + rowbase + half * 8) = om;
        *(s16x8*)(ylo  + rowbase + half * 8) = ol;
    }
}

// ---------------------------------------------------------------- router (fp32-exact)
__global__ __launch_bounds__(256) void router_kernel(const float* __restrict__ h2,
                                                     const void* __restrict__ wr,
                                                     int* topi, float* topw,
                                                     unsigned* counts, const int* flag) {
    int f32 = *flag;
    int n = blockIdx.x, tid = threadIdx.x;
    __shared__ float sm[NE][256];
    float p[NE] = {};
#pragma unroll
    for (int l = 0; l < 4; l++) {
        int dd = l * 256 + tid;
        float hv = h2[(size_t)n * DIMC + dd];
#pragma unroll
        for (int e = 0; e < NE; e++) p[e] += hv * ldf(wr, (size_t)dd * NE + e, f32);
    }
#pragma unroll
    for (int e = 0; e < NE; e++) sm[e][tid] = p[e];
    __syncthreads();
    for (int st = 128; st > 0; st >>= 1) {
        if (tid < st)
#pragma unroll
            for (int e = 0; e < NE; e++) sm[e][tid] += sm[e][tid + st];
        __syncthreads();
    }
    if (tid == 0) {
        float lg[NE];
#pragma unroll
        for (int e = 0; e < NE; e++) lg[e] = sm[e][0];
        int i0 = 0;
        for (int e = 1; e < NE; e++) if (lg[e] > lg[i0]) i0 = e;
        int i1 = -1;
        for (int e = 0; e < NE; e++)
            if (e != i0 && (i1 < 0 || lg[e] > lg[i1])) i1 = e;
        float e1 = __expf(lg[i1] - lg[i0]);
        float inv = 1.0f / (1.0f + e1);
        topi[n * 2] = i0; topi[n * 2 + 1] = i1;
        topw[n * 2] = inv; topw[n * 2 + 1] = e1 * inv;
        atomicAdd(&counts[i0], 1u);
        atomicAdd(&counts[i1], 1u);
    }
}

__global__ void offsets_kernel(const unsigned* counts, unsigned* offsets, unsigned* cursor) {
    if (threadIdx.x == 0 && blockIdx.x == 0) {
        unsigned s = 0;
        for (int e = 0; e < NE; e++) { offsets[e] = s; s += counts[e]; cursor[e] = 0u; }
    }
}

__global__ void scatter_kernel(const int* topi, const unsigned* offsets,
                               unsigned* cursor, int* perm) {
    int n = blockIdx.x * 256 + threadIdx.x;
    if (n >= NTOK) return;
    for (int s = 0; s < 2; s++) {
        int e = topi[n * 2 + s];
        unsigned pos = atomicAdd(&cursor[e], 1u);
        perm[offsets[e] + pos] = n * 2 + s;
    }
}

// ---------------------------------------------------------------- transpose+cast to bf16
// in: raw (flag dtype) [z][R][C] -> out bf16 [z][C][R]; optional 2-way split lo.
__global__ __launch_bounds__(256) void transpose_kernel(const void* __restrict__ in,
                                                        short* __restrict__ out,
                                                        short* __restrict__ out_lo,
                                                        int R, int C, const int* flag) {
    int f32 = *flag;
    __shared__ float t[32][33];
    int r0 = blockIdx.y * 32, c0 = blockIdx.x * 32;
    size_t base = (size_t)blockIdx.z * R * C;
    int tx = threadIdx.x & 31, ty = threadIdx.x >> 5;   // 32 x 8
#pragma unroll
    for (int i = ty; i < 32; i += 8)
        t[i][tx] = ldf(in, base + (size_t)(r0 + i) * C + c0 + tx, f32);
    __syncthreads();
#pragma unroll
    for (int i = ty; i < 32; i += 8) {
        float v = t[tx][i];
        short h0 = f2b(v);
        size_t idx = base + (size_t)(c0 + i) * R + r0 + tx;
        out[idx] = h0;
        if (out_lo) out_lo[idx] = f2b(v - b2f(h0));
    }
}

// ---------------------------------------------------------------- MFMA GEMM for MoE
// MODE 2: he[slot] = gelu(h2b[tok(slot)] @ w1t[e]^T + b1[e])   (A gathered, out bf16)
// MODE 3: moe[tok] += topw[slot] * (he[slot] @ w2t[e]^T)       (atomic epilogue)
template<int MODE>
__global__ __launch_bounds__(256) void mfma_gemm(
    const short* __restrict__ A, const short* __restrict__ Bt,
    short* __restrict__ Cb, const void* __restrict__ bias,
    const int* __restrict__ perm, const unsigned* __restrict__ counts,
    const unsigned* __restrict__ offsets, const float* __restrict__ topw,
    float* __restrict__ moe_out,
    int N, int K, const int* flag)
{
    int e = blockIdx.z;
    int m0 = blockIdx.y * 64, n0 = blockIdx.x * 64;
    int cnt = (int)counts[e];
    if (m0 >= cnt) return;
    unsigned off = offsets[e];
    __shared__ int tokL[64];
    __shared__ float wL[64];
    int tid = threadIdx.x;
    if (tid < 64) {
        int rr = m0 + tid; if (rr >= cnt) rr = cnt - 1;
        int pair = perm[off + rr];
        tokL[tid] = pair >> 1;
        wL[tid] = topw[pair];
    }
    __syncthreads();

    int w = tid >> 6, lane = tid & 63, quad = lane >> 4, l15 = lane & 15;
    int wm = (w >> 1) * 32, wn = (w & 1) * 32;
    int ko = quad * 8;

    const short *a0p, *a1p;
    if (MODE == 2) {
        a0p = A + (size_t)tokL[wm + l15] * K;
        a1p = A + (size_t)tokL[wm + l15 + 16] * K;
    } else {
        int r0 = m0 + wm + l15;      if (r0 >= cnt) r0 = cnt - 1;
        int r1 = m0 + wm + l15 + 16; if (r1 >= cnt) r1 = cnt - 1;
        a0p = A + ((size_t)off + r0) * K;
        a1p = A + ((size_t)off + r1) * K;
    }
    const short* b0p = Bt + (size_t)e * N * K + (size_t)(n0 + wn + l15) * K;
    const short* b1p = b0p + (size_t)16 * K;

    f32x4 acc00 = {0.f,0.f,0.f,0.f}, acc01 = acc00, acc10 = acc00, acc11 = acc00;
#pragma unroll 4
    for (int kk = 0; kk < K; kk += 32) {
        bf16x8 a0 = *(const bf16x8*)(a0p + kk + ko);
        bf16x8 a1 = *(const bf16x8*)(a1p + kk + ko);
        bf16x8 b0 = *(const bf16x8*)(b0p + kk + ko);
        bf16x8 b1 = *(const bf16x8*)(b1p + kk + ko);
        acc00 = __builtin_amdgcn_mfma_f32_16x16x32_bf16(a0, b0, acc00, 0, 0, 0);
        acc01 = __builtin_amdgcn_mfma_f32_16x16x32_bf16(a0, b1, acc01, 0, 0, 0);
        acc10 = __builtin_amdgcn_mfma_f32_16x16x32_bf16(a1, b0, acc10, 0, 0, 0);
        acc11 = __builtin_amdgcn_mfma_f32_16x16x32_bf16(a1, b1, acc11, 0, 0, 0);
    }

    int f32 = (MODE == 2) ? *flag : 0;
#pragma unroll
    for (int mi = 0; mi < 2; mi++) {
#pragma unroll
        for (int ni = 0; ni < 2; ni++) {
            f32x4 acc = (mi == 0) ? (ni == 0 ? acc00 : acc01)
                                  : (ni == 0 ? acc10 : acc11);
            int col = n0 + wn + ni * 16 + l15;
#pragma unroll
            for (int reg = 0; reg < 4; reg++) {
                int row_local = wm + mi * 16 + quad * 4 + reg;
                if (m0 + row_local >= cnt) continue;
                float val = acc[reg];
                if (MODE == 2) {
                    val += ldf(bias, (size_t)e * N + col, f32);
                    val = 0.5f * val * (1.0f + erff(val * 0.70710678118f));
                    Cb[((size_t)off + m0 + row_local) * N + col] = f2b(val);
                } else {
                    int tok = tokL[row_local];
                    atomicAdd(&moe_out[(size_t)tok * N + col], val * wL[row_local]);
                }
            }
        }
    }
}

// ---------------------------------------------------------------- final: out = x2 + moe + sum_s w_s*b2[e_s]
__global__ void final_kernel(const float* x2, const float* moe,
                             const int* topi, const float* topw,
                             const void* b2, void* out, const int* flag) {
    int f32 = *flag;
    int i = blockIdx.x * 256 + threadIdx.x;
    int n = i >> 10, c = i & 1023;
    float v = x2[i] + moe[i];
#pragma unroll
    for (int s = 0; s < 2; s++)
        v += topw[n * 2 + s] * ldf(b2, (size_t)topi[n * 2 + s] * DIMC + c, f32);
    if (f32) ((float*)out)[i] = v;
    else     ((bf16*)out)[i] = __float2bfloat16(v);
}

// ================================================================ launch
extern "C" void kernel_launch(void* const* d_in, const int* in_sizes, int n_in,
                              void* d_out, int out_size, void* d_ws, size_t ws_size,
                              hipStream_t stream) {
    const void* x      = d_in[0];
    const void* ln1_g  = d_in[1];
    const void* ln1_b  = d_in[2];
    const void* w_attn = d_in[3];
    const void* w_proj = d_in[4];
    const void* ln2_g  = d_in[5];
    const void* ln2_b  = d_in[6];
    const void* w_rout = d_in[7];
    const void* w1     = d_in[8];
    const void* b1     = d_in[9];
    const void* w2     = d_in[10];
    const void* b2     = d_in[11];

    const size_t MT = (size_t)NTOK * DIMC;   // 4 M elements
    const size_t MB = 1u << 20;
    char* cws = (char*)d_ws;
    // ---- byte-offset workspace map (high-water 188.25 MB) ----
    // phase A (qkv GEMM):  h split [0,24) + w_attnt [24,36) + qkv [36,84)
    // phase B (attn/proj): y split [0,24) + w_projt [24,28) + qkv [36,84) + x2 [84,100)
    // phase C (router):    h2 [36,52)
    // phase D (MoE):       he [0,64)
    short* hhi    = (short*)(cws + 0 * MB);      // MT bf16
    short* hmid   = (short*)(cws + 8 * MB);
    short* hlo    = (short*)(cws + 16 * MB);
    short* wat_hi = (short*)(cws + 24 * MB);     // 3*DIMC*DIMC bf16 (6 MB)
    short* wat_lo = (short*)(cws + 30 * MB);
    float* qkv    = (float*)(cws + 36 * MB);     // 3*MT fp32 (48 MB)
    short* yhi    = (short*)(cws + 0 * MB);      // reuse h split
    short* ymid   = (short*)(cws + 8 * MB);
    short* ylo    = (short*)(cws + 16 * MB);
    short* wpt_hi = (short*)(cws + 24 * MB);     // DIMC*DIMC bf16 (2 MB)
    short* wpt_lo = (short*)(cws + 26 * MB);
    float* h2     = (float*)(cws + 36 * MB);     // MT fp32 (reuse qkv; dead after router)
    short* he     = (short*)(cws + 0 * MB);      // 2*NTOK x HIDN bf16 (64 MB)
    float* x2     = (float*)(cws + 84 * MB);     // MT fp32
    float* moe    = (float*)(cws + 100 * MB);    // MT fp32
    int*      topi    = (int*)(cws + 116 * MB);          // 32 KB
    float*    topw    = (float*)(topi + 2 * NTOK);       // 32 KB
    unsigned* counts  = (unsigned*)(topw + 2 * NTOK);    // 32 B
    unsigned* offsets = counts + NE;
    unsigned* cursor  = offsets + NE;
    int*      perm    = (int*)(cursor + NE);             // 32 KB
    int*      flag    = (int*)(perm + 2 * NTOK);
    short* h2b  = (short*)(cws + 116 * MB + 256 * 1024); // MT bf16 (8 MB)
    short* w12t = (short*)(cws + 116 * MB + 256 * 1024 + 8 * MB); // 64 MB

    // 0. detect input dtype
    detect_kernel<<<1, 64, 0, stream>>>(x, flag);
    // 1. zero moe accumulator + expert counts
    zero_kernel<<<dim3((MT + 255) / 256), 256, 0, stream>>>(moe, counts);
    // 2. LN1 -> h as 3-way bf16 split (fp32-exact representation)
    ln_kernel<<<NTOK, 256, 0, stream>>>(x, nullptr, ln1_g, ln1_b,
                                        nullptr, hhi, hmid, hlo, flag);
    // 3. w_attnt[3C][C] = w_attn[C][3C]^T  (bf16 hi + lo)
    transpose_kernel<<<dim3(3 * DIMC / 32, DIMC / 32, 1), 256, 0, stream>>>(
        w_attn, wat_hi, wat_lo, DIMC, 3 * DIMC, flag);
    // 4. qkv = h @ w_attn (split MFMA, fp32-grade)
    gemm_split<<<dim3(3 * DIMC / 64, NTOK / 64), 256, 0, stream>>>(
        hhi, hmid, hlo, wat_hi, wat_lo, nullptr, qkv, 3 * DIMC, DIMC, flag);
    // 5. attention (fp32 tiled flash) -> y split
    attn_kernel<<<dim3(TLEN / 64, NBATCH * NHEADS), 256, 0, stream>>>(qkv, yhi, ymid, ylo);
    // 6. w_projt[C][C] = w_proj[C][C]^T  (bf16 hi + lo)
    transpose_kernel<<<dim3(DIMC / 32, DIMC / 32, 1), 256, 0, stream>>>(
        w_proj, wpt_hi, wpt_lo, DIMC, DIMC, flag);
    // 7. x2 = x + y @ w_proj (split MFMA)
    gemm_split<<<dim3(DIMC / 64, NTOK / 64), 256, 0, stream>>>(
        yhi, ymid, ylo, wpt_hi, wpt_lo, x, x2, DIMC, DIMC, flag);
    // 8. LN2 -> h2 (fp32, router) + h2b (bf16, experts)
    ln_kernel<<<NTOK, 256, 0, stream>>>(nullptr, x2, ln2_g, ln2_b,
                                        h2, h2b, nullptr, nullptr, flag);
    // 9. router + top-2 (fp32-exact)
    router_kernel<<<NTOK, 256, 0, stream>>>(h2, w_rout, topi, topw, counts, flag);
    // 10. prefix offsets
    offsets_kernel<<<1, 64, 0, stream>>>(counts, offsets, cursor);
    // 11. scatter token-slot ids by expert
    scatter_kernel<<<NTOK / 256, 256, 0, stream>>>(topi, offsets, cursor, perm);
    // 12. w1t[e][HIDN][DIMC] = w1[e][DIMC][HIDN]^T  (bf16)
    transpose_kernel<<<dim3(HIDN / 32, DIMC / 32, NE), 256, 0, stream>>>(
        w1, w12t, nullptr, DIMC, HIDN, flag);
    // 13. GEMM1: he = gelu(gather(h2b) @ w1t^T + b1)
    mfma_gemm<2><<<dim3(HIDN / 64, NTOK / 64, NE), 256, 0, stream>>>(
        h2b, w12t, he, b1, perm, counts, offsets, topw, nullptr, HIDN, DIMC, flag);
    // 14. w2t[e][DIMC][HIDN] = w2[e][HIDN][DIMC]^T  (bf16, reuses w1t buffer)
    transpose_kernel<<<dim3(DIMC / 32, HIDN / 32, NE), 256, 0, stream>>>(
        w2, w12t, nullptr, HIDN, DIMC, flag);
    // 15. GEMM2: moe[tok] += topw * (he @ w2t^T)
    mfma_gemm<3><<<dim3(DIMC / 64, NTOK / 64, NE), 256, 0, stream>>>(
        he, w12t, nullptr, nullptr, perm, counts, offsets, topw, moe, DIMC, HIDN, flag);
    // 16. out = x2 + moe + sum_s w_s * b2[e_s]
    final_kernel<<<dim3((MT + 255) / 256), 256, 0, stream>>>(x2, moe, topi, topw, b2,
                                                             (void*)d_out, flag);
}

// Round 5
// 1865.880 us; speedup vs baseline: 3.6750x; 1.5933x over previous
//
#include <hip/hip_runtime.h>
#include <hip/hip_bf16.h>
#include <math.h>

typedef __hip_bfloat16 bf16;
typedef __bf16 bf16x8 __attribute__((ext_vector_type(8)));
typedef float f32x4 __attribute__((ext_vector_type(4)));
typedef short s16x8 __attribute__((ext_vector_type(8)));

#define DIMC 1024
#define TLEN 2048
#define NBATCH 2
#define NHEADS 16
#define NE 8
#define NTOK 4096          // B*T
#define HIDN 4096          // 4*DIM
#define LNEPS 1e-5f

// flag-branched input load: f!=0 -> fp32, else bf16
__device__ __forceinline__ float ldf(const void* p, size_t i, int f) {
    return f ? ((const float*)p)[i] : __bfloat162float(((const bf16*)p)[i]);
}
__device__ __forceinline__ short f2b(float v) {
    bf16 h = __float2bfloat16(v);
    return *reinterpret_cast<short*>(&h);
}
__device__ __forceinline__ float b2f(short s) {
    bf16 h = *reinterpret_cast<bf16*>(&s);
    return __bfloat162float(h);
}
// async global->LDS, 16B per lane. LDS dest: wave-uniform base + lane*16.
__device__ __forceinline__ void gload16(const short* g, short* l) {
    __builtin_amdgcn_global_load_lds(
        (const __attribute__((address_space(1))) void*)g,
        (__attribute__((address_space(3))) void*)l, 16, 0, 0);
}

// ---------------------------------------------------------------- dtype detect
__global__ void detect_kernel(const void* x, int* flag) {
    if (threadIdx.x == 0 && blockIdx.x == 0) {
        const bf16* xb = (const bf16*)x;
        float mx = 0.f;
        for (int i = 0; i < 256; i++) {
            float v = fabsf(__bfloat162float(xb[i]));
            if (isnan(v) || isinf(v)) v = 1e30f;
            mx = fmaxf(mx, v);
        }
        flag[0] = (mx < 1e3f) ? 0 : 1;   // 1 = inputs are fp32
    }
}

// ---------------------------------------------------------------- zero init
__global__ void zero_kernel(float* moe_out, unsigned* counts) {
    int i = blockIdx.x * 256 + threadIdx.x;
    if (i < NTOK * DIMC) moe_out[i] = 0.0f;
    if (i < NE) counts[i] = 0u;
}

// ---------------------------------------------------------------- layernorm
// one block per token. Outputs: fp32 (outf) and/or bf16 split:
// o_hi always when non-null; o_mid/o_lo give 3-way split (fp32-exact repr).
__global__ __launch_bounds__(256) void ln_kernel(const void* xr, const float* xf,
                                                 const void* g, const void* b,
                                                 float* outf, short* o_hi,
                                                 short* o_mid, short* o_lo,
                                                 const int* flag) {
    int f32 = *flag;
    int n = blockIdx.x;
    int tid = threadIdx.x;
    __shared__ float red[256];
    float v[4];
#pragma unroll
    for (int l = 0; l < 4; l++) {
        int c = l * 256 + tid;
        v[l] = xr ? ldf(xr, (size_t)n * DIMC + c, f32) : xf[(size_t)n * DIMC + c];
    }
    float s = v[0] + v[1] + v[2] + v[3];
    red[tid] = s; __syncthreads();
    for (int st = 128; st > 0; st >>= 1) { if (tid < st) red[tid] += red[tid + st]; __syncthreads(); }
    float mu = red[0] * (1.0f / DIMC);
    __syncthreads();
    float s2 = 0.f;
#pragma unroll
    for (int l = 0; l < 4; l++) { float d = v[l] - mu; s2 += d * d; }
    red[tid] = s2; __syncthreads();
    for (int st = 128; st > 0; st >>= 1) { if (tid < st) red[tid] += red[tid + st]; __syncthreads(); }
    float var = red[0] * (1.0f / DIMC);
    float rstd = rsqrtf(var + LNEPS);
#pragma unroll
    for (int l = 0; l < 4; l++) {
        int c = l * 256 + tid;
        size_t idx = (size_t)n * DIMC + c;
        float o = (v[l] - mu) * rstd * ldf(g, c, f32) + ldf(b, c, f32);
        if (outf) outf[idx] = o;
        if (o_hi) {
            short h0 = f2b(o);
            o_hi[idx] = h0;
            if (o_mid) {
                float r = o - b2f(h0);
                short h1 = f2b(r);
                o_mid[idx] = h1;
                o_lo[idx] = f2b(r - b2f(h1));
            }
        }
    }
}

// ---------------------------------------------------------------- unified 128x128 MFMA GEMM
// m97-class structure: BM=BN=128, BK=32, 4 waves (each owns a 64x64 quadrant,
// 4x4 fragments of 16x16x32), LDS-staged via global_load_lds width=16,
// 2 barriers per K-step, LDS chunk XOR-swizzle (slot = chunk ^ ((row>>1)&3))
// applied identically on the pre-swizzled global source and the ds_read.
// Fragment layout (verified m89): A[m=lane&15][k=quad*8+j]; B[k][n=lane&15];
// C/D col=lane&15, row=quad*4+reg.
//
// MODE 1: C = (A0+A1+A2) @ Bt^T (+resid)  -- 3-way split A, fp32 out (qkv/proj)
//         flag!=0 (fp32 weights): adds (A0+A1)*Blo terms (Blo direct-global).
// MODE 2: he[slot] = gelu(A[tok(slot)] @ Bt[e]^T + bias[e])  -> bf16 out
// MODE 3: moe[tok] += topw[slot] * (A[off+slot] @ Bt[e]^T)   -> atomic f32
template<int MODE>
__global__ __launch_bounds__(256) void gemm128(
    const short* __restrict__ A0, const short* __restrict__ A1,
    const short* __restrict__ A2,
    const short* __restrict__ Bt, const short* __restrict__ Blo,
    const void* __restrict__ resid, float* __restrict__ Cf,
    short* __restrict__ Cb, const void* __restrict__ bias,
    const int* __restrict__ perm, const unsigned* __restrict__ counts,
    const unsigned* __restrict__ offsets, const float* __restrict__ topw,
    float* __restrict__ moe_out,
    int N, int K, const int* flag)
{
    constexpr int NT = (MODE == 1) ? 4 : 2;       // A tiles (1 or 3) + B tile
    __shared__ __align__(16) short tiles[NT * 4096];   // each tile: 128 rows x 32 k
    __shared__ int tokLs[128];
    __shared__ float wLs[128];

    int e = (MODE >= 2) ? blockIdx.z : 0;
    int m0 = blockIdx.y * 128, n0 = blockIdx.x * 128;
    int cnt = 0; unsigned off = 0;
    if (MODE >= 2) {
        cnt = (int)counts[e];
        if (m0 >= cnt) return;
        off = offsets[e];
    }
    int tid = threadIdx.x;
    int f32 = *flag;

    if (MODE >= 2) {
        if (tid < 128) {
            int rr = m0 + tid; if (rr >= cnt) rr = cnt - 1;
            int pair = perm[off + rr];
            tokLs[tid] = pair >> 1;
            wLs[tid] = topw[pair];
        }
        __syncthreads();
    }

    // ---- staging setup: thread stages LDS chunks (tid) and (tid+256) of each
    // tile; chunk L -> row L>>2, slot L&3; content = global chunk slot^((row>>1)&3).
    int r0 = tid >> 2;                        // rows r0 and r0+64 (same swizzle)
    int c0 = (tid & 3) ^ ((r0 >> 1) & 3);     // swizzled global chunk
    int wb = (tid & 192) * 8;                 // wave-uniform LDS elem base (instr 0)
    size_t cofs = (size_t)c0 * 8;

    const short* BTe = (MODE >= 2) ? Bt + (size_t)e * N * K : Bt;
    const short* gb0 = BTe + (size_t)(n0 + r0) * K + cofs;
    const short* gb1 = BTe + (size_t)(n0 + r0 + 64) * K + cofs;

    size_t arow0, arow1;
    if (MODE == 1)      { arow0 = m0 + r0;      arow1 = m0 + r0 + 64; }
    else if (MODE == 2) { arow0 = tokLs[r0];    arow1 = tokLs[r0 + 64]; }
    else {
        int rr0 = m0 + r0;      if (rr0 >= cnt) rr0 = cnt - 1;
        int rr1 = m0 + r0 + 64; if (rr1 >= cnt) rr1 = cnt - 1;
        arow0 = off + rr0; arow1 = off + rr1;
    }
    const short* ga0 = A0 + arow0 * K + cofs;
    const short* ga1 = A0 + arow1 * K + cofs;
    const short *gm0 = nullptr, *gm1 = nullptr, *gl0 = nullptr, *gl1 = nullptr;
    if (MODE == 1) {
        gm0 = A1 + arow0 * K + cofs; gm1 = A1 + arow1 * K + cofs;
        gl0 = A2 + arow0 * K + cofs; gl1 = A2 + arow1 * K + cofs;
    }

    short* tA0 = tiles;
    short* tA1 = tiles + 4096;
    short* tA2 = tiles + 8192;
    short* tB  = tiles + (NT - 1) * 4096;

    // ---- fragment read offsets (constant across K-steps)
    int w = tid >> 6, lane = tid & 63, quad = lane >> 4, l15 = lane & 15;
    int wm = (w >> 1) * 64, wn = (w & 1) * 64;
    int offA[4], offB[4];
#pragma unroll
    for (int i = 0; i < 4; i++) {
        int ra = wm + i * 16 + l15;
        offA[i] = ra * 32 + ((quad ^ ((ra >> 1) & 3)) * 8);
        int rb = wn + i * 16 + l15;
        offB[i] = rb * 32 + ((quad ^ ((rb >> 1) & 3)) * 8);
    }

    f32x4 acc[4][4];
#pragma unroll
    for (int i = 0; i < 4; i++)
#pragma unroll
        for (int j = 0; j < 4; j++) acc[i][j] = (f32x4){0.f, 0.f, 0.f, 0.f};

    for (int kt = 0; kt < K; kt += 32) {
        if (kt) __syncthreads();               // prev compute done reading LDS
        if (MODE == 1) {
            gload16(ga0 + kt, tA0 + wb); gload16(ga1 + kt, tA0 + wb + 2048);
            gload16(gm0 + kt, tA1 + wb); gload16(gm1 + kt, tA1 + wb + 2048);
            gload16(gl0 + kt, tA2 + wb); gload16(gl1 + kt, tA2 + wb + 2048);
        } else {
            gload16(ga0 + kt, tA0 + wb); gload16(ga1 + kt, tA0 + wb + 2048);
        }
        gload16(gb0 + kt, tB + wb); gload16(gb1 + kt, tB + wb + 2048);
        __syncthreads();                       // vmcnt(0) drain: LDS tile ready

        bf16x8 b[4];
#pragma unroll
        for (int ni = 0; ni < 4; ni++) b[ni] = *(const bf16x8*)(tB + offB[ni]);
        if (MODE == 1) {
#pragma unroll
            for (int mi = 0; mi < 4; mi++) {
                bf16x8 ah = *(const bf16x8*)(tA0 + offA[mi]);
                bf16x8 am = *(const bf16x8*)(tA1 + offA[mi]);
                bf16x8 al = *(const bf16x8*)(tA2 + offA[mi]);
#pragma unroll
                for (int ni = 0; ni < 4; ni++) {
                    acc[mi][ni] = __builtin_amdgcn_mfma_f32_16x16x32_bf16(ah, b[ni], acc[mi][ni], 0, 0, 0);
                    acc[mi][ni] = __builtin_amdgcn_mfma_f32_16x16x32_bf16(am, b[ni], acc[mi][ni], 0, 0, 0);
                    acc[mi][ni] = __builtin_amdgcn_mfma_f32_16x16x32_bf16(al, b[ni], acc[mi][ni], 0, 0, 0);
                }
            }
            if (f32) {   // fp32 weights: B-lo terms, direct-global (correctness path)
#pragma unroll
                for (int ni = 0; ni < 4; ni++) {
                    bf16x8 bl = *(const bf16x8*)(Blo + (size_t)(n0 + wn + ni * 16 + l15) * K + kt + quad * 8);
#pragma unroll
                    for (int mi = 0; mi < 4; mi++) {
                        bf16x8 ah = *(const bf16x8*)(tA0 + offA[mi]);
                        bf16x8 am = *(const bf16x8*)(tA1 + offA[mi]);
                        acc[mi][ni] = __builtin_amdgcn_mfma_f32_16x16x32_bf16(ah, bl, acc[mi][ni], 0, 0, 0);
                        acc[mi][ni] = __builtin_amdgcn_mfma_f32_16x16x32_bf16(am, bl, acc[mi][ni], 0, 0, 0);
                    }
                }
            }
        } else {
#pragma unroll
            for (int mi = 0; mi < 4; mi++) {
                bf16x8 a = *(const bf16x8*)(tA0 + offA[mi]);
#pragma unroll
                for (int ni = 0; ni < 4; ni++)
                    acc[mi][ni] = __builtin_amdgcn_mfma_f32_16x16x32_bf16(a, b[ni], acc[mi][ni], 0, 0, 0);
            }
        }
    }

    // ---- epilogue (layouts identical to R3-verified kernels)
#pragma unroll
    for (int mi = 0; mi < 4; mi++) {
#pragma unroll
        for (int ni = 0; ni < 4; ni++) {
            int col = n0 + wn + ni * 16 + l15;
#pragma unroll
            for (int reg = 0; reg < 4; reg++) {
                int rl = wm + mi * 16 + quad * 4 + reg;   // local row
                float val = acc[mi][ni][reg];
                if (MODE == 1) {
                    int row = m0 + rl;
                    float rv = resid ? ldf(resid, (size_t)row * N + col, f32) : 0.0f;
                    Cf[(size_t)row * N + col] = val + rv;
                } else if (MODE == 2) {
                    if (m0 + rl < cnt) {
                        val += ldf(bias, (size_t)e * N + col, f32);
                        val = 0.5f * val * (1.0f + erff(val * 0.70710678118f));
                        Cb[((size_t)off + m0 + rl) * N + col] = f2b(val);
                    }
                } else {
                    if (m0 + rl < cnt)
                        atomicAdd(&moe_out[(size_t)tokLs[rl] * N + col], val * wLs[rl]);
                }
            }
        }
    }
}

// ---------------------------------------------------------------- attention: fp32 tiled flash
#define KB 64
#define KSTRIDE 72   // pad 64->72 floats: staging writes 2-way, reads conflict-free

__global__ __launch_bounds__(256) void attn_kernel(const float* __restrict__ qkv,
                                                   short* __restrict__ yhi,
                                                   short* __restrict__ ymid,
                                                   short* __restrict__ ylo) {
    int qblk = gridDim.x - 1 - blockIdx.x;   // longest causal blocks first
    int bh = blockIdx.y; int b = bh >> 4, h = bh & 15;
    int tid = threadIdx.x;
    int lane = tid & 63;
    int wave = tid >> 6;
    int qid = lane & 15;       // query within wave
    int dpart = lane >> 4;     // 0..3: owns dims dpart*16..dpart*16+15
    int q = qblk * 64 + wave * 16 + qid;

    __shared__ float Ks[KB * KSTRIDE];
    __shared__ float Vs[KB * KSTRIDE];

    const float* base = qkv + (size_t)b * TLEN * 3 * DIMC;

    float qv[16];
    {
        const float* qrow = base + (size_t)q * 3 * DIMC + h * 64 + dpart * 16;
#pragma unroll
        for (int j = 0; j < 16; j++) qv[j] = qrow[j] * 0.125f;   // 1/sqrt(64)
    }
    float acc[16];
#pragma unroll
    for (int j = 0; j < 16; j++) acc[j] = 0.f;
    float m = -INFINITY, l = 0.f;

    int ntiles = qblk + 1;                 // causal: keys 0 .. qblk*64+63
    for (int t = 0; t < ntiles; t++) {
        int k0 = t * KB;
        __syncthreads();                   // protect previous tile's readers
#pragma unroll
        for (int p4 = 0; p4 < 4; p4++) {
            int idx = tid + p4 * 256;
            int r = idx >> 4, c4 = idx & 15;
            const float* krow = base + (size_t)(k0 + r) * 3 * DIMC + DIMC + h * 64 + c4 * 4;
            *(f32x4*)&Ks[r * KSTRIDE + c4 * 4] = *(const f32x4*)krow;
            *(f32x4*)&Vs[r * KSTRIDE + c4 * 4] = *(const f32x4*)(krow + DIMC);
        }
        __syncthreads();
        bool diag = (t == ntiles - 1);
        for (int kk = 0; kk < KB; kk++) {
            const float* kr = &Ks[kk * KSTRIDE + dpart * 16];
            float s0 = 0.f, s1 = 0.f, s2 = 0.f, s3 = 0.f;
            {
                f32x4 c0 = *(const f32x4*)(kr);
                f32x4 c1 = *(const f32x4*)(kr + 4);
                f32x4 c2 = *(const f32x4*)(kr + 8);
                f32x4 c3 = *(const f32x4*)(kr + 12);
#pragma unroll
                for (int j = 0; j < 4; j++) {
                    s0 += qv[j]      * c0[j];
                    s1 += qv[4 + j]  * c1[j];
                    s2 += qv[8 + j]  * c2[j];
                    s3 += qv[12 + j] * c3[j];
                }
            }
            float p = (s0 + s1) + (s2 + s3);
            p += __shfl_xor(p, 16);        // reduce across the 4 dim-partitions
            p += __shfl_xor(p, 32);
            if (diag && (k0 + kk > q)) p = -INFINITY;
            if (p > m) {                   // rescale only on new max (exact)
                float alpha = __expf(m - p);   // m=-inf first time -> 0
                l *= alpha;
#pragma unroll
                for (int j = 0; j < 16; j++) acc[j] *= alpha;
                m = p;
            }
            float w = __expf(p - m);
            l += w;
            const float* vr = &Vs[kk * KSTRIDE + dpart * 16];
#pragma unroll
            for (int c = 0; c < 4; c++) {
                f32x4 vc = *(const f32x4*)(vr + c * 4);
#pragma unroll
                for (int j = 0; j < 4; j++) acc[c * 4 + j] += w * vc[j];
            }
        }
    }

    float invl = 1.0f / l;
    size_t rowbase = (size_t)(b * TLEN + q) * DIMC + h * 64 + dpart * 16;
#pragma unroll
    for (int half = 0; half < 2; half++) {
        s16x8 oh, om, ol;
#pragma unroll
        for (int j = 0; j < 8; j++) {
            float v = acc[half * 8 + j] * invl;
            short h0 = f2b(v);
            float r = v - b2f(h0);
            short h1 = f2b(r);
            oh[j] = h0; om[j] = h1; ol[j] = f2b(r - b2f(h1));
        }
        *(s16x8*)(yhi  + rowbase + half * 8) = oh;
        *(s16x8*)(ymid + rowbase + half * 8) = om;
        *(s16x8*)(ylo  + rowbase + half * 8) = ol;
    }
}

// ---------------------------------------------------------------- router (fp32-exact)
__global__ __launch_bounds__(256) void router_kernel(const float* __restrict__ h2,
                                                     const void* __restrict__ wr,
                                                     int* topi, float* topw,
                                                     unsigned* counts, const int* flag) {
    int f32 = *flag;
    int n = blockIdx.x, tid = threadIdx.x;
    __shared__ float sm[NE][256];
    float p[NE] = {};
#pragma unroll
    for (int l = 0; l < 4; l++) {
        int dd = l * 256 + tid;
        float hv = h2[(size_t)n * DIMC + dd];
#pragma unroll
        for (int e = 0; e < NE; e++) p[e] += hv * ldf(wr, (size_t)dd * NE + e, f32);
    }
#pragma unroll
    for (int e = 0; e < NE; e++) sm[e][tid] = p[e];
    __syncthreads();
    for (int st = 128; st > 0; st >>= 1) {
        if (tid < st)
#pragma unroll
            for (int e = 0; e < NE; e++) sm[e][tid] += sm[e][tid + st];
        __syncthreads();
    }
    if (tid == 0) {
        float lg[NE];
#pragma unroll
        for (int e = 0; e < NE; e++) lg[e] = sm[e][0];
        int i0 = 0;
        for (int e = 1; e < NE; e++) if (lg[e] > lg[i0]) i0 = e;
        int i1 = -1;
        for (int e = 0; e < NE; e++)
            if (e != i0 && (i1 < 0 || lg[e] > lg[i1])) i1 = e;
        float e1 = __expf(lg[i1] - lg[i0]);
        float inv = 1.0f / (1.0f + e1);
        topi[n * 2] = i0; topi[n * 2 + 1] = i1;
        topw[n * 2] = inv; topw[n * 2 + 1] = e1 * inv;
        atomicAdd(&counts[i0], 1u);
        atomicAdd(&counts[i1], 1u);
    }
}

__global__ void offsets_kernel(const unsigned* counts, unsigned* offsets, unsigned* cursor) {
    if (threadIdx.x == 0 && blockIdx.x == 0) {
        unsigned s = 0;
        for (int e = 0; e < NE; e++) { offsets[e] = s; s += counts[e]; cursor[e] = 0u; }
    }
}

__global__ void scatter_kernel(const int* topi, const unsigned* offsets,
                               unsigned* cursor, int* perm) {
    int n = blockIdx.x * 256 + threadIdx.x;
    if (n >= NTOK) return;
    for (int s = 0; s < 2; s++) {
        int e = topi[n * 2 + s];
        unsigned pos = atomicAdd(&cursor[e], 1u);
        perm[offsets[e] + pos] = n * 2 + s;
    }
}

// ---------------------------------------------------------------- transpose+cast to bf16
// in: raw (flag dtype) [z][R][C] -> out bf16 [z][C][R]; optional 2-way split lo.
__global__ __launch_bounds__(256) void transpose_kernel(const void* __restrict__ in,
                                                        short* __restrict__ out,
                                                        short* __restrict__ out_lo,
                                                        int R, int C, const int* flag) {
    int f32 = *flag;
    __shared__ float t[32][33];
    int r0 = blockIdx.y * 32, c0 = blockIdx.x * 32;
    size_t base = (size_t)blockIdx.z * R * C;
    int tx = threadIdx.x & 31, ty = threadIdx.x >> 5;   // 32 x 8
#pragma unroll
    for (int i = ty; i < 32; i += 8)
        t[i][tx] = ldf(in, base + (size_t)(r0 + i) * C + c0 + tx, f32);
    __syncthreads();
#pragma unroll
    for (int i = ty; i < 32; i += 8) {
        float v = t[tx][i];
        short h0 = f2b(v);
        size_t idx = base + (size_t)(c0 + i) * R + r0 + tx;
        out[idx] = h0;
        if (out_lo) out_lo[idx] = f2b(v - b2f(h0));
    }
}

// ---------------------------------------------------------------- final: out = x2 + moe + sum_s w_s*b2[e_s]
__global__ void final_kernel(const float* x2, const float* moe,
                             const int* topi, const float* topw,
                             const void* b2, void* out, const int* flag) {
    int f32 = *flag;
    int i = blockIdx.x * 256 + threadIdx.x;
    int n = i >> 10, c = i & 1023;
    float v = x2[i] + moe[i];
#pragma unroll
    for (int s = 0; s < 2; s++)
        v += topw[n * 2 + s] * ldf(b2, (size_t)topi[n * 2 + s] * DIMC + c, f32);
    if (f32) ((float*)out)[i] = v;
    else     ((bf16*)out)[i] = __float2bfloat16(v);
}

// ================================================================ launch
extern "C" void kernel_launch(void* const* d_in, const int* in_sizes, int n_in,
                              void* d_out, int out_size, void* d_ws, size_t ws_size,
                              hipStream_t stream) {
    const void* x      = d_in[0];
    const void* ln1_g  = d_in[1];
    const void* ln1_b  = d_in[2];
    const void* w_attn = d_in[3];
    const void* w_proj = d_in[4];
    const void* ln2_g  = d_in[5];
    const void* ln2_b  = d_in[6];
    const void* w_rout = d_in[7];
    const void* w1     = d_in[8];
    const void* b1     = d_in[9];
    const void* w2     = d_in[10];
    const void* b2     = d_in[11];

    const size_t MT = (size_t)NTOK * DIMC;   // 4 M elements
    const size_t MB = 1u << 20;
    char* cws = (char*)d_ws;
    // ---- byte-offset workspace map (high-water 188.25 MB) ----
    short* hhi    = (short*)(cws + 0 * MB);      // MT bf16
    short* hmid   = (short*)(cws + 8 * MB);
    short* hlo    = (short*)(cws + 16 * MB);
    short* wat_hi = (short*)(cws + 24 * MB);     // 3*DIMC*DIMC bf16 (6 MB)
    short* wat_lo = (short*)(cws + 30 * MB);
    float* qkv    = (float*)(cws + 36 * MB);     // 3*MT fp32 (48 MB)
    short* yhi    = (short*)(cws + 0 * MB);      // reuse h split
    short* ymid   = (short*)(cws + 8 * MB);
    short* ylo    = (short*)(cws + 16 * MB);
    short* wpt_hi = (short*)(cws + 24 * MB);     // DIMC*DIMC bf16 (2 MB)
    short* wpt_lo = (short*)(cws + 26 * MB);
    float* h2     = (float*)(cws + 36 * MB);     // MT fp32 (reuse qkv; dead after router)
    short* he     = (short*)(cws + 0 * MB);      // 2*NTOK x HIDN bf16 (64 MB)
    float* x2     = (float*)(cws + 84 * MB);     // MT fp32
    float* moe    = (float*)(cws + 100 * MB);    // MT fp32
    int*      topi    = (int*)(cws + 116 * MB);          // 32 KB
    float*    topw    = (float*)(topi + 2 * NTOK);       // 32 KB
    unsigned* counts  = (unsigned*)(topw + 2 * NTOK);    // 32 B
    unsigned* offsets = counts + NE;
    unsigned* cursor  = offsets + NE;
    int*      perm    = (int*)(cursor + NE);             // 32 KB
    int*      flag    = (int*)(perm + 2 * NTOK);
    short* h2b  = (short*)(cws + 116 * MB + 256 * 1024); // MT bf16 (8 MB)
    short* w12t = (short*)(cws + 116 * MB + 256 * 1024 + 8 * MB); // 64 MB

    // 0. detect input dtype
    detect_kernel<<<1, 64, 0, stream>>>(x, flag);
    // 1. zero moe accumulator + expert counts
    zero_kernel<<<dim3((MT + 255) / 256), 256, 0, stream>>>(moe, counts);
    // 2. LN1 -> h as 3-way bf16 split (fp32-exact representation)
    ln_kernel<<<NTOK, 256, 0, stream>>>(x, nullptr, ln1_g, ln1_b,
                                        nullptr, hhi, hmid, hlo, flag);
    // 3. w_attnt[3C][C] = w_attn[C][3C]^T  (bf16 hi + lo)
    transpose_kernel<<<dim3(3 * DIMC / 32, DIMC / 32, 1), 256, 0, stream>>>(
        w_attn, wat_hi, wat_lo, DIMC, 3 * DIMC, flag);
    // 4. qkv = h @ w_attn (split MFMA, fp32-grade)
    gemm128<1><<<dim3(3 * DIMC / 128, NTOK / 128), 256, 0, stream>>>(
        hhi, hmid, hlo, wat_hi, wat_lo, nullptr, qkv,
        nullptr, nullptr, nullptr, nullptr, nullptr, nullptr, nullptr,
        3 * DIMC, DIMC, flag);
    // 5. attention (fp32 tiled flash) -> y split
    attn_kernel<<<dim3(TLEN / 64, NBATCH * NHEADS), 256, 0, stream>>>(qkv, yhi, ymid, ylo);
    // 6. w_projt[C][C] = w_proj[C][C]^T  (bf16 hi + lo)
    transpose_kernel<<<dim3(DIMC / 32, DIMC / 32, 1), 256, 0, stream>>>(
        w_proj, wpt_hi, wpt_lo, DIMC, DIMC, flag);
    // 7. x2 = x + y @ w_proj (split MFMA)
    gemm128<1><<<dim3(DIMC / 128, NTOK / 128), 256, 0, stream>>>(
        yhi, ymid, ylo, wpt_hi, wpt_lo, x, x2,
        nullptr, nullptr, nullptr, nullptr, nullptr, nullptr, nullptr,
        DIMC, DIMC, flag);
    // 8. LN2 -> h2 (fp32, router) + h2b (bf16, experts)
    ln_kernel<<<NTOK, 256, 0, stream>>>(nullptr, x2, ln2_g, ln2_b,
                                        h2, h2b, nullptr, nullptr, flag);
    // 9. router + top-2 (fp32-exact)
    router_kernel<<<NTOK, 256, 0, stream>>>(h2, w_rout, topi, topw, counts, flag);
    // 10. prefix offsets
    offsets_kernel<<<1, 64, 0, stream>>>(counts, offsets, cursor);
    // 11. scatter token-slot ids by expert
    scatter_kernel<<<NTOK / 256, 256, 0, stream>>>(topi, offsets, cursor, perm);
    // 12. w1t[e][HIDN][DIMC] = w1[e][DIMC][HIDN]^T  (bf16)
    transpose_kernel<<<dim3(HIDN / 32, DIMC / 32, NE), 256, 0, stream>>>(
        w1, w12t, nullptr, DIMC, HIDN, flag);
    // 13. GEMM1: he = gelu(gather(h2b) @ w1t^T + b1)
    gemm128<2><<<dim3(HIDN / 128, NTOK / 128, NE), 256, 0, stream>>>(
        h2b, nullptr, nullptr, w12t, nullptr, nullptr, nullptr,
        he, b1, perm, counts, offsets, topw, nullptr, HIDN, DIMC, flag);
    // 14. w2t[e][DIMC][HIDN] = w2[e][HIDN][DIMC]^T  (bf16, reuses w1t buffer)
    transpose_kernel<<<dim3(DIMC / 32, HIDN / 32, NE), 256, 0, stream>>>(
        w2, w12t, nullptr, HIDN, DIMC, flag);
    // 15. GEMM2: moe[tok] += topw * (he @ w2t^T)
    gemm128<3><<<dim3(DIMC / 128, NTOK / 128, NE), 256, 0, stream>>>(
        he, nullptr, nullptr, w12t, nullptr, nullptr, nullptr,
        nullptr, nullptr, perm, counts, offsets, topw, moe, DIMC, HIDN, flag);
    // 16. out = x2 + moe + sum_s w_s * b2[e_s]
    final_kernel<<<dim3((MT + 255) / 256), 256, 0, stream>>>(x2, moe, topi, topw, b2,
                                                             (void*)d_out, flag);
}